// Round 1
// 67.189 us; speedup vs baseline: 1.0072x; 1.0072x over previous
//
#include <hip/hip_runtime.h>
#include <math.h>

// QPU layer: quaternion power + chained Hamilton product + normalize.
// x: (P, 4*C_IN) as [r|i|j|k], weight: (C_OUT, C_IN), bias: (C_OUT)
// out: (P, 4*C_OUT) as [r|i|j|k]
//
// Round 6: quarter-chain parallelism. The Hamilton fold is associative, so
// each 64-step chain is split into FOUR 16-step quarter-chains on four waves
// (8192 chain-waves -> 8 waves/SIMD at 2 blocks/CU, double round-5 occupancy),
// combined via three extra Hamilton products through LDS. 64-VGPR budget
// enforced by __launch_bounds__(1024, 8).

typedef float v2f __attribute__((ext_vector_type(2)));

#define C_IN   64
#define C_OUT  128
#define POS_PER_BLOCK 4
#define NQ     4                         // quarter-chains per position
#define QLEN   (C_IN / NQ)               // 16 channels per quarter-chain
#define BLOCK  (POS_PER_BLOCK * NQ * 64) // 1024 threads = 16 waves
#define WSTR2  (C_OUT / 2 + 1)           // float2 row stride 65 (odd -> no pow2 bank stride)

#define INV_2PI 0.15915494309189535f

__global__ __launch_bounds__(BLOCK, 8) void qpu_kernel(
    const float* __restrict__ x,
    const float* __restrict__ weight,
    const float* __restrict__ bias,
    float* __restrict__ out,
    int P)
{
    __shared__ float  w_s[C_IN * WSTR2 * 2];            // transposed weight, ~33.3 KB
    __shared__ float4 pre[POS_PER_BLOCK][C_IN];         // (theta0/2pi, i/n, j/n, k/n)  4 KB
    __shared__ v2f    part[POS_PER_BLOCK][NQ - 1][4][64]; // quarters 1..3 partials, 24 KB

    const int tid  = threadIdx.x;
    const int lane = tid & 63;
    const int wave = tid >> 6;
    const int sub  = wave >> 2;          // position within block (0..3)
    const int q    = wave & 3;           // which quarter of the chain

    // ---- stage weight transposed into LDS (float4 global loads, 2 iters) ----
    // w_s float index for (c,o): c*130 + o
    {
        const float4* w4 = (const float4*)weight;
        #pragma unroll
        for (int idx = tid; idx < (C_OUT * C_IN) / 4; idx += BLOCK) {
            const float4 v = w4[idx];
            const int o  = idx >> 4;
            const int c0 = (idx & 15) * 4;
            w_s[(c0 + 0) * (2 * WSTR2) + o] = v.x;
            w_s[(c0 + 1) * (2 * WSTR2) + o] = v.y;
            w_s[(c0 + 2) * (2 * WSTR2) + o] = v.z;
            w_s[(c0 + 3) * (2 * WSTR2) + o] = v.w;
        }
    }

    const int pos = blockIdx.x * POS_PER_BLOCK + sub;
    const bool valid = (pos < P);

    // ---- per-position preprocessing: threads t<64 of each 256-thread sub ----
    {
        const int t = tid & 255;
        if (valid && t < C_IN) {
            const int c = t;
            const float* xb = x + (size_t)pos * (4 * C_IN);
            const float r = xb[c];
            const float i = xb[C_IN + c];
            const float j = xb[2 * C_IN + c];
            const float k = xb[3 * C_IN + c];
            const float rc = fminf(fmaxf(r, -0.999999f), 0.999999f);  // CLAMP = 1-1e-6
            const float th0 = acosf(rc) * INV_2PI;                    // pre-fold to revolutions
            const float inv = rsqrtf(fmaf(i, i, fmaf(j, j, fmaf(k, k, 1e-12f))));
            pre[sub][c] = make_float4(th0, i * inv, j * inv, k * inv);
        }
    }
    __syncthreads();

    // bias pair for outputs (2*lane, 2*lane+1), folded to revolution domain
    const v2f b2 = ((const v2f*)bias)[lane] * INV_2PI;
    const v2f* __restrict__ w2 = (const v2f*)w_s;

    // quarter-chain left fold: c in [q*16, q*16+16)
    v2f pr = 1.0f, pi = 0.0f, pj = 0.0f, pk = 0.0f;

    if (valid) {
        const int c0 = q * QLEN;
        #pragma unroll 4
        for (int cc = 0; cc < QLEN; ++cc) {
            const int c = c0 + cc;
            const float4 p4 = pre[sub][c];            // wave-uniform -> LDS broadcast
            const v2f    w  = w2[c * WSTR2 + lane];   // ds_read_b64, conflict-free
            const v2f    rev = w * p4.x + b2;         // |rev| < 0.25 (revolutions)
            v2f s, ct;
            s.x  = __builtin_amdgcn_sinf(rev.x);      // v_sin_f32: sin(rev*2pi)
            s.y  = __builtin_amdgcn_sinf(rev.y);
            ct.x = __builtin_amdgcn_cosf(rev.x);
            ct.y = __builtin_amdgcn_cosf(rev.y);
            const v2f qi = p4.y * s;
            const v2f qj = p4.z * s;
            const v2f qk = p4.w * s;
            // p = p (x) q  (Hamilton, p on the left)
            const v2f nr = pr * ct - pi * qi - pj * qj - pk * qk;
            const v2f ni = pr * qi + pi * ct + pj * qk - pk * qj;
            const v2f nj = pr * qj - pi * qk + pj * ct + pk * qi;
            const v2f nk = pr * qk + pi * qj - pj * qi + pk * ct;
            pr = nr; pi = ni; pj = nj; pk = nk;
        }
    }

    // quarters 1..3 publish partials
    if (q != 0) {
        part[sub][q - 1][0][lane] = pr;
        part[sub][q - 1][1][lane] = pi;
        part[sub][q - 1][2][lane] = pj;
        part[sub][q - 1][3][lane] = pk;
    }
    __syncthreads();

    if (!valid || q != 0) return;

    // combine: total = Q0 (x) Q1 (x) Q2 (x) Q3, left to right
    #pragma unroll
    for (int qq = 0; qq < NQ - 1; ++qq) {
        const v2f Br = part[sub][qq][0][lane];
        const v2f Bi = part[sub][qq][1][lane];
        const v2f Bj = part[sub][qq][2][lane];
        const v2f Bk = part[sub][qq][3][lane];
        const v2f tr = pr * Br - pi * Bi - pj * Bj - pk * Bk;
        const v2f ti = pr * Bi + pi * Br + pj * Bk - pk * Bj;
        const v2f tj = pr * Bj - pi * Bk + pj * Br + pk * Bi;
        const v2f tk = pr * Bk + pi * Bj - pj * Bi + pk * Br;
        pr = tr; pi = ti; pj = tj; pk = tk;
    }

    // packed normalize
    const v2f n2 = pr * pr + pi * pi + pj * pj + pk * pk + 1e-12f;
    v2f invn;
    invn.x = rsqrtf(n2.x);
    invn.y = rsqrtf(n2.y);

    // coalesced float2 stores: lane l covers out channels 2l, 2l+1
    float* ob = out + (size_t)pos * (4 * C_OUT);
    ((v2f*)(ob            ))[lane] = pr * invn;
    ((v2f*)(ob +     C_OUT))[lane] = pi * invn;
    ((v2f*)(ob + 2 * C_OUT))[lane] = pj * invn;
    ((v2f*)(ob + 3 * C_OUT))[lane] = pk * invn;
}

extern "C" void kernel_launch(void* const* d_in, const int* in_sizes, int n_in,
                              void* d_out, int out_size, void* d_ws, size_t ws_size,
                              hipStream_t stream) {
    const float* x      = (const float*)d_in[0];
    const float* weight = (const float*)d_in[1];
    const float* bias   = (const float*)d_in[2];
    float* out          = (float*)d_out;

    const int P = in_sizes[0] / (4 * C_IN);   // B*T = 2048
    const int grid = (P + POS_PER_BLOCK - 1) / POS_PER_BLOCK;

    qpu_kernel<<<grid, BLOCK, 0, stream>>>(x, weight, bias, out, P);
}